// Round 1
// baseline (187.610 us; speedup 1.0000x reference)
//
#include <hip/hip_runtime.h>
#include <stdint.h>

typedef __attribute__((ext_vector_type(4))) float  float4v;
typedef __attribute__((ext_vector_type(8))) __bf16 bf16x8;
typedef __attribute__((ext_vector_type(8))) unsigned short ushort8;

#define B_DIM 8192
#define H_DIM 1024
#define O_DIM 1024

static __device__ __forceinline__ unsigned short f32_to_bf16(float f) {
  union { float f; unsigned int u; } v; v.f = f;
  unsigned int u = v.u;
  unsigned int r = u + 0x7FFFu + ((u >> 16) & 1u);  // round-to-nearest-even
  return (unsigned short)(r >> 16);
}

// ---------------------------------------------------------------------------
// prep_inputs: single launch doing both weight transpose and state cast.
//  blocks [0,1280): basis[4][H][O] + prj_w[H][O] -> Wt bf16 [5][O][H]
//  blocks [1280,5376): state fp32 [B][H] -> Abf bf16 [B][H]
// ---------------------------------------------------------------------------
__global__ void prep_inputs(const float* __restrict__ state,
                            const float* __restrict__ basis,
                            const float* __restrict__ prjw,
                            unsigned short* __restrict__ Abf,
                            unsigned short* __restrict__ Wt) {
  __shared__ __align__(16) unsigned short t[64 * 72];
  int bb = blockIdx.x;
  int tid = threadIdx.x;
  if (bb < 1280) {
    int m = bb >> 8, panel = bb & 255;
    int o0 = (panel & 15) * 64, h0 = (panel >> 4) * 64;
    const float* src = (m < 4) ? (basis + (size_t)m * H_DIM * O_DIM) : prjw;  // [H][O]
    int r  = tid >> 4;
    int c4 = (tid & 15) * 4;
#pragma unroll
    for (int p = 0; p < 4; ++p) {
      int h = r + p * 16;
      float4v v = *(const float4v*)(src + (size_t)(h0 + h) * O_DIM + o0 + c4);
      t[(c4 + 0) * 72 + h] = f32_to_bf16(v.x);
      t[(c4 + 1) * 72 + h] = f32_to_bf16(v.y);
      t[(c4 + 2) * 72 + h] = f32_to_bf16(v.z);
      t[(c4 + 3) * 72 + h] = f32_to_bf16(v.w);
    }
    __syncthreads();
#pragma unroll
    for (int i = 0; i < 2; ++i) {
      int C = i * 256 + tid;
      int o = C >> 3, cc = C & 7;
      ushort8 val = *(const ushort8*)(t + o * 72 + cc * 8);
      *(ushort8*)(Wt + ((size_t)m * O_DIM + o0 + o) * H_DIM + h0 + cc * 8) = val;
    }
  } else {
    int i = (bb - 1280) * 256 + tid;  // 8 elems per thread
    float4v v0 = ((const float4v*)state)[i * 2];
    float4v v1 = ((const float4v*)state)[i * 2 + 1];
    ushort8 o;
    o[0] = f32_to_bf16(v0.x); o[1] = f32_to_bf16(v0.y);
    o[2] = f32_to_bf16(v0.z); o[3] = f32_to_bf16(v0.w);
    o[4] = f32_to_bf16(v1.x); o[5] = f32_to_bf16(v1.y);
    o[6] = f32_to_bf16(v1.z); o[7] = f32_to_bf16(v1.w);
    ((ushort8*)Abf)[i] = o;
  }
}

// ---------------------------------------------------------------------------
// Fused 5-mode GEMM, software-pipelined K-loop.
//  Tile 128(B) x 64(O); waves 2x2, wave-tile 64x32. BK=32, 32 stages.
//  Double-buffered LDS (2 x 28KB): issue stage s+1 -> compute stage s ->
//  __syncthreads. The vmcnt drain now lands AFTER a full compute window
//  (R3: drain immediately after issue = 54% stall at MfmaUtil 46%).
//  Chunk swizzle pos = q ^ ((row>>1)&3) on 64B rows: conflict-free b128 reads.
//  Coeff prep fused in (reads se/curv/gate directly; cfg kernel deleted).
// ---------------------------------------------------------------------------
__global__ __launch_bounds__(256, 2)
void gemm_fused(const unsigned short* __restrict__ A,
                const unsigned short* __restrict__ Wt,
                const float* __restrict__ se, const float* __restrict__ curv,
                const float* __restrict__ gw, const float* __restrict__ gb,
                const float* __restrict__ prjb,
                float* __restrict__ out) {
  __shared__ __align__(16) unsigned char smem[59904];
  // stage buf s&1 at s*28672: [A 128x32 bf16 = 8192B][B 5 x 64x32 = 20480B]
  float* scf = (float*)(smem + 57344);  // 5 x 128 fp32

  const int tid  = threadIdx.x;
  const int lane = tid & 63;
  const int wave = tid >> 6;
  const int row0 = blockIdx.x * 128;
  const int col0 = blockIdx.y * 64;
  const int wrow = (wave >> 1) * 64;   // 0 or 64
  const int wcol = (wave & 1) * 32;    // 0 or 32
  const int q  = lane >> 4;
  const int ln = lane & 15;

  // ---- fused coeff prep: coeff[m][row] for this block's 128 rows
  if (tid < 128) {
    int b = row0 + tid;
    float s = se[b];
    float l0 = fmaf(s, gw[0], gb[0]);
    float l1 = fmaf(s, gw[1], gb[1]);
    float l2 = fmaf(s, gw[2], gb[2]);
    float l3 = fmaf(s, gw[3], gb[3]);
    float mx = fmaxf(fmaxf(l0, l1), fmaxf(l2, l3));
    float e0 = __expf(l0 - mx), e1 = __expf(l1 - mx);
    float e2 = __expf(l2 - mx), e3 = __expf(l3 - mx);
    float mix = 1.0f / (1.0f + __expf(-curv[b]));
    float inv = mix / (e0 + e1 + e2 + e3);
    scf[0 * 128 + tid] = e0 * inv;
    scf[1 * 128 + tid] = e1 * inv;
    scf[2 * 128 + tid] = e2 * inv;
    scf[3 * 128 + tid] = e3 * inv;
    scf[4 * 128 + tid] = 1.0f - mix;
  }

  // ---- staging descriptors (16B chunks; stored pos holds global chunk
  //      g = pos ^ ((row>>1)&3); rows are 32 elems = 64B = 4 chunks)
  const unsigned short* gA[2];
  unsigned int ldsA[2];
#pragma unroll
  for (int j = 0; j < 2; ++j) {
    int C = (wave * 2 + j) * 64 + lane;     // 0..511
    int row = C >> 2, pos = C & 3;
    int g = pos ^ ((row >> 1) & 3);
    gA[j] = A + (size_t)(row0 + row) * H_DIM + g * 8;
    ldsA[j] = (wave * 2 + j) * 1024;        // wave-uniform base (HW adds lane*16)
  }
  const unsigned short* gB[5];
  unsigned int ldsBbase = 8192 + wave * 1024;
  {
    int C = wave * 64 + lane;               // 0..255
    int row = C >> 2, pos = C & 3;
    int g = pos ^ ((row >> 1) & 3);
#pragma unroll
    for (int m = 0; m < 5; ++m)
      gB[m] = Wt + (size_t)m * O_DIM * H_DIM + (size_t)(col0 + row) * H_DIM + g * 8;
  }

  float4v acc[5][4][2];
#pragma unroll
  for (int m = 0; m < 5; ++m)
#pragma unroll
    for (int i = 0; i < 4; ++i)
#pragma unroll
      for (int j = 0; j < 2; ++j)
        acc[m][i][j] = (float4v){0.f, 0.f, 0.f, 0.f};

#define ISSUE_STAGE(s)                                                          \
  do {                                                                          \
    const int _buf = (s) & 1;                                                   \
    const int _k = (s) * 32;                                                    \
    unsigned char* _base = smem + _buf * 28672;                                 \
    _Pragma("unroll")                                                           \
    for (int _j = 0; _j < 2; ++_j)                                              \
      __builtin_amdgcn_global_load_lds(                                         \
          (const __attribute__((address_space(1))) void*)(gA[_j] + _k),         \
          (__attribute__((address_space(3))) void*)(_base + ldsA[_j]), 16, 0, 0);\
    _Pragma("unroll")                                                           \
    for (int _m = 0; _m < 5; ++_m)                                              \
      __builtin_amdgcn_global_load_lds(                                         \
          (const __attribute__((address_space(1))) void*)(gB[_m] + _k),         \
          (__attribute__((address_space(3))) void*)(_base + ldsBbase + _m * 4096),\
          16, 0, 0);                                                            \
  } while (0)

#define COMPUTE_STAGE(s)                                                        \
  do {                                                                          \
    const unsigned short* _sA = (const unsigned short*)(smem + ((s) & 1) * 28672);\
    const unsigned short* _sB = _sA + 4096;                                     \
    bf16x8 _af[4];                                                              \
    _Pragma("unroll")                                                           \
    for (int _t = 0; _t < 4; ++_t) {                                            \
      int _ra = wrow + _t * 16 + ln;                                            \
      int _ps = q ^ ((_ra >> 1) & 3);                                           \
      _af[_t] = *(const bf16x8*)(_sA + _ra * 32 + _ps * 8);                     \
    }                                                                           \
    _Pragma("unroll")                                                           \
    for (int _m = 0; _m < 5; ++_m) {                                            \
      bf16x8 _b0, _b1;                                                          \
      {                                                                         \
        int _rb = wcol + ln;                                                    \
        int _p0 = q ^ ((_rb >> 1) & 3);                                         \
        _b0 = *(const bf16x8*)(_sB + _m * 2048 + _rb * 32 + _p0 * 8);           \
        int _r1 = wcol + 16 + ln;                                               \
        int _p1 = q ^ ((_r1 >> 1) & 3);                                         \
        _b1 = *(const bf16x8*)(_sB + _m * 2048 + _r1 * 32 + _p1 * 8);           \
      }                                                                         \
      _Pragma("unroll")                                                         \
      for (int _ti = 0; _ti < 4; ++_ti) {                                       \
        acc[_m][_ti][0] = __builtin_amdgcn_mfma_f32_16x16x32_bf16(              \
            _af[_ti], _b0, acc[_m][_ti][0], 0, 0, 0);                           \
        acc[_m][_ti][1] = __builtin_amdgcn_mfma_f32_16x16x32_bf16(              \
            _af[_ti], _b1, acc[_m][_ti][1], 0, 0, 0);                           \
      }                                                                         \
    }                                                                           \
  } while (0)

  ISSUE_STAGE(0);
  __syncthreads();  // stage 0 landed; scf visible
#pragma unroll 2
  for (int s = 0; s < 31; ++s) {
    ISSUE_STAGE(s + 1);   // prefetch into the other buffer
    COMPUTE_STAGE(s);     // full compute window overlaps the loads
    __syncthreads();      // drain s+1 loads + all waves done reading buf s
  }
  COMPUTE_STAGE(31);

  // ---- epilogue: mode-combine -> LDS repack (fp32, pitch 68) -> float4 stores
  __syncthreads();
  float* fbuf = (float*)smem;  // 128 x 68 fp32 = 34816 B (scf at 57344 safe)
#pragma unroll
  for (int ti = 0; ti < 4; ++ti) {
    int rl = wrow + ti * 16 + q * 4;
#pragma unroll
    for (int tj = 0; tj < 2; ++tj) {
      int cc = wcol + tj * 16 + ln;
#pragma unroll
      for (int r = 0; r < 4; ++r) {
        float v = 0.f;
#pragma unroll
        for (int m = 0; m < 5; ++m)
          v += scf[m * 128 + rl + r] * acc[m][ti][tj][r];
        fbuf[(rl + r) * 68 + cc] = v;
      }
    }
  }
  __syncthreads();
#pragma unroll
  for (int i = 0; i < 8; ++i) {
    int L = i * 256 + tid;          // 2048 float4s = 128 rows x 16
    int row = L >> 4, c4 = L & 15;
    float4v v = *(const float4v*)(fbuf + row * 68 + c4 * 4);
    float cb = scf[4 * 128 + row];
    float4v pb = *(const float4v*)(prjb + col0 + c4 * 4);
    v += cb * pb;
    *(float4v*)(out + (size_t)(row0 + row) * O_DIM + col0 + c4 * 4) = v;
  }
#undef ISSUE_STAGE
#undef COMPUTE_STAGE
}

// ---------------------------------------------------------------------------
extern "C" void kernel_launch(void* const* d_in, const int* in_sizes, int n_in,
                              void* d_out, int out_size, void* d_ws, size_t ws_size,
                              hipStream_t stream) {
  const float* state = (const float*)d_in[0];
  const float* se    = (const float*)d_in[1];
  const float* curv  = (const float*)d_in[2];
  const float* basis = (const float*)d_in[3];
  const float* gw    = (const float*)d_in[4];
  const float* gb    = (const float*)d_in[5];
  const float* prjw  = (const float*)d_in[6];
  const float* prjb  = (const float*)d_in[7];
  float* out = (float*)d_out;

  char* ws = (char*)d_ws;
  unsigned short* Abf = (unsigned short*)ws;                               // 16 MB
  unsigned short* Wt  = (unsigned short*)(ws + (size_t)16 * 1024 * 1024);  // 10 MB

  prep_inputs<<<5376, 256, 0, stream>>>(state, basis, prjw, Abf, Wt);
  dim3 gg(B_DIM / 128, O_DIM / 64);
  gemm_fused<<<gg, 256, 0, stream>>>(Abf, Wt, se, curv, gw, gb, prjb, out);
}

// Round 2
// 180.593 us; speedup vs baseline: 1.0389x; 1.0389x over previous
//
#include <hip/hip_runtime.h>
#include <stdint.h>

typedef __attribute__((ext_vector_type(4))) float  float4v;
typedef __attribute__((ext_vector_type(8))) __bf16 bf16x8;
typedef __attribute__((ext_vector_type(8))) unsigned short ushort8;

#define B_DIM 8192
#define H_DIM 1024
#define O_DIM 1024

static __device__ __forceinline__ unsigned short f32_to_bf16(float f) {
  union { float f; unsigned int u; } v; v.f = f;
  unsigned int u = v.u;
  unsigned int r = u + 0x7FFFu + ((u >> 16) & 1u);  // round-to-nearest-even
  return (unsigned short)(r >> 16);
}

// ---------------------------------------------------------------------------
// prep_inputs: unchanged this round (isolating the gemm schedule change).
//  blocks [0,1280): basis[4][H][O] + prj_w[H][O] -> Wt bf16 [5][O][H]
//  blocks [1280,5376): state fp32 [B][H] -> Abf bf16 [B][H]
// ---------------------------------------------------------------------------
__global__ void prep_inputs(const float* __restrict__ state,
                            const float* __restrict__ basis,
                            const float* __restrict__ prjw,
                            unsigned short* __restrict__ Abf,
                            unsigned short* __restrict__ Wt) {
  __shared__ __align__(16) unsigned short t[64 * 72];
  int bb = blockIdx.x;
  int tid = threadIdx.x;
  if (bb < 1280) {
    int m = bb >> 8, panel = bb & 255;
    int o0 = (panel & 15) * 64, h0 = (panel >> 4) * 64;
    const float* src = (m < 4) ? (basis + (size_t)m * H_DIM * O_DIM) : prjw;  // [H][O]
    int r  = tid >> 4;
    int c4 = (tid & 15) * 4;
#pragma unroll
    for (int p = 0; p < 4; ++p) {
      int h = r + p * 16;
      float4v v = *(const float4v*)(src + (size_t)(h0 + h) * O_DIM + o0 + c4);
      t[(c4 + 0) * 72 + h] = f32_to_bf16(v.x);
      t[(c4 + 1) * 72 + h] = f32_to_bf16(v.y);
      t[(c4 + 2) * 72 + h] = f32_to_bf16(v.z);
      t[(c4 + 3) * 72 + h] = f32_to_bf16(v.w);
    }
    __syncthreads();
#pragma unroll
    for (int i = 0; i < 2; ++i) {
      int C = i * 256 + tid;
      int o = C >> 3, cc = C & 7;
      ushort8 val = *(const ushort8*)(t + o * 72 + cc * 8);
      *(ushort8*)(Wt + ((size_t)m * O_DIM + o0 + o) * H_DIM + h0 + cc * 8) = val;
    }
  } else {
    int i = (bb - 1280) * 256 + tid;  // 8 elems per thread
    float4v v0 = ((const float4v*)state)[i * 2];
    float4v v1 = ((const float4v*)state)[i * 2 + 1];
    ushort8 o;
    o[0] = f32_to_bf16(v0.x); o[1] = f32_to_bf16(v0.y);
    o[2] = f32_to_bf16(v0.z); o[3] = f32_to_bf16(v0.w);
    o[4] = f32_to_bf16(v1.x); o[5] = f32_to_bf16(v1.y);
    o[6] = f32_to_bf16(v1.z); o[7] = f32_to_bf16(v1.w);
    ((ushort8*)Abf)[i] = o;
  }
}

// ---------------------------------------------------------------------------
// R2: Fused 5-mode GEMM, counted-vmcnt deep pipeline (T3/T4).
//  Tile 256(B) x 64(O); 512 thr = 8 waves (4 row x 2 col), wave-tile 64x32.
//  BK=32, 32 stages. 3-buffer LDS ring (3 x 36KB): issue stage s+3 into the
//  buffer stage s just vacated; steady-state wait = vmcnt(2n) per wave
//  (never 0 in the loop) -> each stage's loads have ~2 compute windows of
//  latency cover instead of 1.  Raw s_barrier (no compiler vmcnt drain).
//  Load duty: waves 0-3 stage A (4 x 1KB chunks), waves 4-7 stage B (5 x 1KB).
//  Chunk swizzle pos = q ^ ((row>>1)&3) on 64B rows (proven conflict-free).
// ---------------------------------------------------------------------------
__global__ __launch_bounds__(512, 2)
void gemm_fused(const unsigned short* __restrict__ A,
                const unsigned short* __restrict__ Wt,
                const float* __restrict__ se, const float* __restrict__ curv,
                const float* __restrict__ gw, const float* __restrict__ gb,
                const float* __restrict__ prjb,
                float* __restrict__ out) {
  // ring buf b at b*36864: [A 256x32 bf16 = 16384B][B 5 x 64x32 = 20480B]
  __shared__ __align__(16) unsigned char smem[115712];
  float* scf = (float*)(smem + 110592);  // 5 x 256 fp32

  const int tid  = threadIdx.x;
  const int lane = tid & 63;
  const int wave = tid >> 6;
  const int row0 = blockIdx.x * 256;
  const int col0 = blockIdx.y * 64;
  const int wrow = (wave >> 1) * 64;   // 0,64,128,192
  const int wcol = (wave & 1) * 32;    // 0 or 32
  const int q  = lane >> 4;
  const int ln = lane & 15;

  // ---- fused coeff prep: coeff[m][row] for this block's 256 rows
  if (tid < 256) {
    int b = row0 + tid;
    float s = se[b];
    float l0 = fmaf(s, gw[0], gb[0]);
    float l1 = fmaf(s, gw[1], gb[1]);
    float l2 = fmaf(s, gw[2], gb[2]);
    float l3 = fmaf(s, gw[3], gb[3]);
    float mx = fmaxf(fmaxf(l0, l1), fmaxf(l2, l3));
    float e0 = __expf(l0 - mx), e1 = __expf(l1 - mx);
    float e2 = __expf(l2 - mx), e3 = __expf(l3 - mx);
    float mix = 1.0f / (1.0f + __expf(-curv[b]));
    float inv = mix / (e0 + e1 + e2 + e3);
    scf[0 * 256 + tid] = e0 * inv;
    scf[1 * 256 + tid] = e1 * inv;
    scf[2 * 256 + tid] = e2 * inv;
    scf[3 * 256 + tid] = e3 * inv;
    scf[4 * 256 + tid] = 1.0f - mix;
  }

  // ---- staging descriptors.  1KB wave-chunk = 16 rows x 32k bf16.
  //      Within a chunk lane l -> row = c*16 + (l>>2), pos = l&3; the stored
  //      pos holds global 16B-chunk g = pos ^ ((row>>1)&3)  (swizzle).
  const unsigned short* gsrc[5];
  unsigned int ldsoff[5];
  if (wave < 4) {
#pragma unroll
    for (int j = 0; j < 4; ++j) {
      int c = wave * 4 + j;                 // A chunk 0..15
      int row = c * 16 + (lane >> 2);
      int pos = lane & 3;
      int g = pos ^ ((row >> 1) & 3);
      gsrc[j] = A + (size_t)(row0 + row) * H_DIM + g * 8;
      ldsoff[j] = c * 1024;
    }
    gsrc[4] = gsrc[0]; ldsoff[4] = ldsoff[0];  // unused
  } else {
#pragma unroll
    for (int j = 0; j < 5; ++j) {
      int c = (wave - 4) * 5 + j;           // B chunk 0..19
      int m = c >> 2;                       // mode (4 chunks per mode)
      int r = (c & 3) * 16 + (lane >> 2);   // row within mode slab (0..63)
      int pos = lane & 3;
      int g = pos ^ ((r >> 1) & 3);
      gsrc[j] = Wt + (size_t)m * O_DIM * H_DIM + (size_t)(col0 + r) * H_DIM + g * 8;
      ldsoff[j] = 16384 + c * 1024;
    }
  }

  float4v acc[5][4][2];
#pragma unroll
  for (int m = 0; m < 5; ++m)
#pragma unroll
    for (int i = 0; i < 4; ++i)
#pragma unroll
      for (int j = 0; j < 2; ++j)
        acc[m][i][j] = (float4v){0.f, 0.f, 0.f, 0.f};

#define ISSUE_STAGE(koff, boff)                                                 \
  do {                                                                          \
    if (wave < 4) {                                                             \
      _Pragma("unroll")                                                         \
      for (int _j = 0; _j < 4; ++_j)                                            \
        __builtin_amdgcn_global_load_lds(                                       \
            (const __attribute__((address_space(1))) void*)(gsrc[_j] + (koff)), \
            (__attribute__((address_space(3))) void*)(smem + (boff) + ldsoff[_j]),\
            16, 0, 0);                                                          \
    } else {                                                                    \
      _Pragma("unroll")                                                         \
      for (int _j = 0; _j < 5; ++_j)                                            \
        __builtin_amdgcn_global_load_lds(                                       \
            (const __attribute__((address_space(1))) void*)(gsrc[_j] + (koff)), \
            (__attribute__((address_space(3))) void*)(smem + (boff) + ldsoff[_j]),\
            16, 0, 0);                                                          \
    }                                                                           \
  } while (0)

  // per-wave counted waits: waves 0-3 issue 4/stage, waves 4-7 issue 5/stage
#define WAITV_STEADY                                                            \
  do {                                                                          \
    if (wave < 4) asm volatile("s_waitcnt vmcnt(8)" ::: "memory");              \
    else          asm volatile("s_waitcnt vmcnt(10)" ::: "memory");             \
  } while (0)
#define WAITV_ONE                                                               \
  do {                                                                          \
    if (wave < 4) asm volatile("s_waitcnt vmcnt(4)" ::: "memory");              \
    else          asm volatile("s_waitcnt vmcnt(5)" ::: "memory");              \
  } while (0)
#define WAITV_ZERO asm volatile("s_waitcnt vmcnt(0)" ::: "memory")

#define COMPUTE_STAGE(boff)                                                     \
  do {                                                                          \
    const unsigned short* _sA = (const unsigned short*)(smem + (boff));         \
    const unsigned short* _sB = _sA + 8192;                                     \
    __builtin_amdgcn_s_setprio(1);                                              \
    bf16x8 _af[4];                                                              \
    _Pragma("unroll")                                                           \
    for (int _t = 0; _t < 4; ++_t) {                                            \
      int _ra = wrow + _t * 16 + ln;                                            \
      int _ps = q ^ ((_ra >> 1) & 3);                                           \
      _af[_t] = *(const bf16x8*)(_sA + _ra * 32 + _ps * 8);                     \
    }                                                                           \
    _Pragma("unroll")                                                           \
    for (int _m = 0; _m < 5; ++_m) {                                            \
      bf16x8 _b0, _b1;                                                          \
      {                                                                         \
        int _rb = wcol + ln;                                                    \
        int _p0 = q ^ ((_rb >> 1) & 3);                                         \
        _b0 = *(const bf16x8*)(_sB + _m * 2048 + _rb * 32 + _p0 * 8);           \
        int _r1 = wcol + 16 + ln;                                               \
        int _p1 = q ^ ((_r1 >> 1) & 3);                                         \
        _b1 = *(const bf16x8*)(_sB + _m * 2048 + _r1 * 32 + _p1 * 8);           \
      }                                                                         \
      _Pragma("unroll")                                                         \
      for (int _ti = 0; _ti < 4; ++_ti) {                                       \
        acc[_m][_ti][0] = __builtin_amdgcn_mfma_f32_16x16x32_bf16(              \
            _af[_ti], _b0, acc[_m][_ti][0], 0, 0, 0);                           \
        acc[_m][_ti][1] = __builtin_amdgcn_mfma_f32_16x16x32_bf16(              \
            _af[_ti], _b1, acc[_m][_ti][1], 0, 0, 0);                           \
      }                                                                         \
    }                                                                           \
    __builtin_amdgcn_s_setprio(0);                                              \
  } while (0)

  // ---- prologue: fill the 3-deep ring
  ISSUE_STAGE(0, 0u);
  ISSUE_STAGE(32, 36864u);
  ISSUE_STAGE(64, 73728u);
  asm volatile("s_waitcnt lgkmcnt(0)" ::: "memory");  // scf ds_writes retired
  WAITV_STEADY;                                       // stage 0 landed (own wave)
  __builtin_amdgcn_s_barrier();                       // all waves: stage 0 ready

  unsigned int boff = 0u;
  int kk = 96;
  for (int s = 0; s < 29; ++s) {
    COMPUTE_STAGE(boff);               // reads buf[s%3]
    __builtin_amdgcn_s_barrier();      // all waves done reading buf[s%3]
    ISSUE_STAGE(kk, boff);             // stage s+3 into the vacated buffer
    WAITV_STEADY;                      // stage s+1 landed (own wave)
    __builtin_amdgcn_s_barrier();      // all waves: stage s+1 ready
    kk += 32;
    boff = (boff == 73728u) ? 0u : boff + 36864u;
  }
  // ---- tail: stages 29,30,31 (no more issues)
  COMPUTE_STAGE(boff);                 // s=29
  WAITV_ONE;                           // stage 30 landed
  __builtin_amdgcn_s_barrier();
  boff = (boff == 73728u) ? 0u : boff + 36864u;
  COMPUTE_STAGE(boff);                 // s=30
  WAITV_ZERO;                          // stage 31 landed
  __builtin_amdgcn_s_barrier();
  boff = (boff == 73728u) ? 0u : boff + 36864u;
  COMPUTE_STAGE(boff);                 // s=31

  // ---- epilogue: mode-combine -> LDS repack (fp32, pitch 68) -> float4 stores
  __syncthreads();
  float* fbuf = (float*)smem;  // 256 x 68 fp32 = 69632 B (scf at 110592 safe)
#pragma unroll
  for (int ti = 0; ti < 4; ++ti) {
    int rl = wrow + ti * 16 + q * 4;
#pragma unroll
    for (int tj = 0; tj < 2; ++tj) {
      int cc = wcol + tj * 16 + ln;
#pragma unroll
      for (int r = 0; r < 4; ++r) {
        float v = 0.f;
#pragma unroll
        for (int m = 0; m < 5; ++m)
          v += scf[m * 256 + rl + r] * acc[m][ti][tj][r];
        fbuf[(rl + r) * 68 + cc] = v;
      }
    }
  }
  __syncthreads();
#pragma unroll
  for (int i = 0; i < 8; ++i) {
    int L = i * 512 + tid;          // 4096 float4s = 256 rows x 16
    int row = L >> 4, c4 = L & 15;
    float4v v = *(const float4v*)(fbuf + row * 68 + c4 * 4);
    float cb = scf[4 * 256 + row];
    float4v pb = *(const float4v*)(prjb + col0 + c4 * 4);
    v += cb * pb;
    *(float4v*)(out + (size_t)(row0 + row) * O_DIM + col0 + c4 * 4) = v;
  }
#undef ISSUE_STAGE
#undef WAITV_STEADY
#undef WAITV_ONE
#undef WAITV_ZERO
#undef COMPUTE_STAGE
}

// ---------------------------------------------------------------------------
extern "C" void kernel_launch(void* const* d_in, const int* in_sizes, int n_in,
                              void* d_out, int out_size, void* d_ws, size_t ws_size,
                              hipStream_t stream) {
  const float* state = (const float*)d_in[0];
  const float* se    = (const float*)d_in[1];
  const float* curv  = (const float*)d_in[2];
  const float* basis = (const float*)d_in[3];
  const float* gw    = (const float*)d_in[4];
  const float* gb    = (const float*)d_in[5];
  const float* prjw  = (const float*)d_in[6];
  const float* prjb  = (const float*)d_in[7];
  float* out = (float*)d_out;

  char* ws = (char*)d_ws;
  unsigned short* Abf = (unsigned short*)ws;                               // 16 MB
  unsigned short* Wt  = (unsigned short*)(ws + (size_t)16 * 1024 * 1024);  // 10 MB

  prep_inputs<<<5376, 256, 0, stream>>>(state, basis, prjw, Abf, Wt);
  dim3 gg(B_DIM / 256, O_DIM / 64);
  gemm_fused<<<gg, 512, 0, stream>>>(Abf, Wt, se, curv, gw, gb, prjb, out);
}